// Round 4
// baseline (245.169 us; speedup 1.0000x reference)
//
#include <hip/hip_runtime.h>
#include <hip/hip_cooperative_groups.h>
#include <stdint.h>

namespace cg = cooperative_groups;

#define NB 4
#define SS 192
#define NI 256

typedef __attribute__((ext_vector_type(8))) short bf16x8;
typedef __attribute__((ext_vector_type(4))) float f32x4;

struct Params {
  const float *h_head, *h_dep, *h_sib, *W, *U, *V, *Z, *bias;
  float *out;
  float *partial, *hU, *hV, *dZ, *s_hd, *s_hs, *s_ds;
  uint16_t *HW, *HD, *HS;
};

__device__ __forceinline__ uint16_t f2bf(float f) {
  union { float f; uint32_t u; } v; v.f = f;
  return (uint16_t)((v.u + 0x7FFFu + ((v.u >> 16) & 1u)) >> 16);
}

__device__ __forceinline__ uint32_t bfmul2(uint32_t x, uint32_t y) {
  union { float f; uint32_t u; } xa, xb, ya, yb, r0, r1;
  xa.u = x << 16;        ya.u = y << 16;
  xb.u = x & 0xFFFF0000u; yb.u = y & 0xFFFF0000u;
  r0.f = xa.f * ya.f;
  r1.f = xb.f * yb.f;
  uint32_t lo = (r0.u + 0x7FFFu + ((r0.u >> 16) & 1u)) >> 16;
  uint32_t hi = (r1.u + 0x7FFFu + ((r1.u >> 16) & 1u)) >> 16;
  return lo | (hi << 16);
}

// =================== cooperative mega-kernel ===================
__global__ __launch_bounds__(256, 4) void k_mega(Params p) {
  cg::grid_group grid = cg::this_grid();
  __shared__ __align__(16) unsigned char Atile[24576];
  __shared__ float wred[NI];
  __shared__ float red[4];
  const int bi = blockIdx.x, tid = threadIdx.x;
  const int gsz = gridDim.x;

  // ---------- Phase A: W_tri partial sums (2048 chunks) + HD/HS bf16 ----------
  for (int c = bi; c < 2048; c += gsz) {
    const float4* w4 = (const float4*)(p.W + (size_t)c * 8192);
    float s = 0.f;
    #pragma unroll
    for (int j = 0; j < 8; ++j) { float4 v = w4[j * 256 + tid]; s += v.x + v.y + v.z + v.w; }
    for (int off = 32; off > 0; off >>= 1) s += __shfl_down(s, off, 64);
    if ((tid & 63) == 0) red[tid >> 6] = s;
    __syncthreads();
    if (tid == 0) p.partial[c] = red[0] + red[1] + red[2] + red[3];
    __syncthreads();
  }
  for (int r = bi; r < NB * SS; r += gsz) {
    const int g = r * NI + tid;
    p.HD[g] = f2bf(p.h_dep[g]);
    p.HS[g] = f2bf(p.h_sib[g]);
  }
  grid.sync();

  // ---------- Phase B: w_red finish + HW + fused proj->scores ----------
  {
    float s = 0.f;
    #pragma unroll
    for (int q = 0; q < 8; ++q) s += p.partial[8 * tid + q];
    wred[tid] = s;
  }
  __syncthreads();
  for (int r = bi; r < NB * SS; r += gsz) {
    const int g = r * NI + tid;
    p.HW[g] = f2bf(p.h_head[g] * wred[tid]);
  }
  {
    float* ahf = (float*)Atile;           // [4][256] f32
    float* tf  = (float*)Atile + 1024;    // [4][256] f32
    for (int u = bi; u < 576; u += gsz) {
      const int which = u / 192, rem = u % 192;
      const int b = rem / 48, x0 = (rem % 48) * 4;
      const float* A  = (which == 2) ? p.h_dep : p.h_head;
      const float* M  = (which == 0) ? p.U : (which == 1) ? p.V : p.Z;
      const float* Bm = (which == 0) ? p.h_dep : p.h_sib;
      float* outp = (which == 0) ? p.s_hd : (which == 1) ? p.s_hs : p.s_ds;
      __syncthreads();
      #pragma unroll
      for (int r = 0; r < 4; ++r) ahf[r * NI + tid] = A[(b * SS + x0 + r) * NI + tid];
      __syncthreads();
      float ta[4] = {};
      for (int i = 0; i < NI; ++i) {
        const float m = M[i * NI + tid];
        #pragma unroll
        for (int r = 0; r < 4; ++r) ta[r] += ahf[r * NI + i] * m;
      }
      #pragma unroll
      for (int r = 0; r < 4; ++r) tf[r * NI + tid] = ta[r];
      __syncthreads();
      if (tid < SS) {
        const float4* brow = (const float4*)(Bm + (b * SS + tid) * NI);
        float acc[4] = {};
        for (int c = 0; c < NI / 4; ++c) {
          const float4 bv = brow[c];
          #pragma unroll
          for (int r = 0; r < 4; ++r) {
            const float4 av = ((const float4*)(tf + r * NI))[c];
            acc[r] += av.x * bv.x + av.y * bv.y + av.z * bv.z + av.w * bv.w;
          }
        }
        #pragma unroll
        for (int r = 0; r < 4; ++r) outp[(b * SS + x0 + r) * SS + tid] = acc[r];
      }
    }
  }
  grid.sync();

  // ---------- Phase D: 3072 GEMM units (b, d, s-tile of 48) ----------
  {
    const int lane = tid & 63, w = tid >> 6;
    const int n0 = w * 48;
    const int fr = lane & 15, lg = lane >> 4;
    const int kb = lg * 8;
    const float bias0 = p.bias[0];
    for (int u = bi; u < 3072; u += gsz) {
      const int b = u / 768, rem = u % 768;
      const int d = rem >> 2, s0 = (rem & 3) * 48;
      __syncthreads();
      const int col8 = tid & 31;
      const uint4 hd4 = *(const uint4*)(p.HD + (b * SS + d) * NI + col8 * 8);
      #pragma unroll
      for (int it = 0; it < 6; ++it) {
        const int row = it * 8 + (tid >> 5);
        const uint4 hs4 = *(const uint4*)(p.HS + (b * SS + s0 + row) * NI + col8 * 8);
        uint4 a4;
        a4.x = bfmul2(hs4.x, hd4.x);
        a4.y = bfmul2(hs4.y, hd4.y);
        a4.z = bfmul2(hs4.z, hd4.z);
        a4.w = bfmul2(hs4.w, hd4.w);
        const int swz = ((row << 9) | (col8 << 4)) ^ ((row & 7) << 4);
        *(uint4*)(Atile + swz) = a4;
      }
      __syncthreads();
      const uint16_t* hwb = p.HW + (b * SS) * NI;
      f32x4 acc[3][3] = {};
      #pragma unroll
      for (int ks = 0; ks < 8; ++ks) {
        const int k = ks * 32 + kb;
        bf16x8 a[3], bb[3];
        #pragma unroll
        for (int mt = 0; mt < 3; ++mt) {
          const int r = mt * 16 + fr;
          a[mt] = *reinterpret_cast<const bf16x8*>(Atile + ((((r << 9) + k * 2)) ^ ((r & 7) << 4)));
        }
        #pragma unroll
        for (int nt = 0; nt < 3; ++nt)
          bb[nt] = *reinterpret_cast<const bf16x8*>(hwb + (n0 + nt * 16 + fr) * NI + k);
        #pragma unroll
        for (int mt = 0; mt < 3; ++mt)
          #pragma unroll
          for (int nt = 0; nt < 3; ++nt)
            acc[mt][nt] = __builtin_amdgcn_mfma_f32_16x16x32_bf16(a[mt], bb[nt], acc[mt][nt], 0, 0, 0);
      }
      float c0[3];
      #pragma unroll
      for (int nt = 0; nt < 3; ++nt)
        c0[nt] = p.s_hd[(b * SS + n0 + nt * 16 + fr) * SS + d] + bias0;
      #pragma unroll
      for (int mt = 0; mt < 3; ++mt) {
        const int s = s0 + mt * 16 + lg * 4;
        const float4 ds4 = *(const float4*)(p.s_ds + (b * SS + d) * SS + s);
        #pragma unroll
        for (int nt = 0; nt < 3; ++nt) {
          const int h = n0 + nt * 16 + fr;
          const float4 hs4 = *(const float4*)(p.s_hs + (b * SS + h) * SS + s);
          float4 v;
          v.x = acc[mt][nt][0] + c0[nt] + hs4.x + ds4.x;
          v.y = acc[mt][nt][1] + c0[nt] + hs4.y + ds4.y;
          v.z = acc[mt][nt][2] + c0[nt] + hs4.z + ds4.z;
          v.w = acc[mt][nt][3] + c0[nt] + hs4.w + ds4.w;
          *(float4*)(p.out + ((size_t)(b * SS + h) * SS + d) * SS + s) = v;
        }
      }
    }
  }
}

// =================== fallback: R1's validated 5-kernel pipeline ===================
__global__ void k_wtri_partial(const float* __restrict__ W, float* __restrict__ partial) {
  const int bi = blockIdx.x, tid = threadIdx.x;
  const float4* p = (const float4*)(W + (size_t)bi * 16384);
  float s = 0.f;
  #pragma unroll
  for (int it = 0; it < 16; ++it) {
    float4 v = p[it * 256 + tid];
    s += v.x + v.y + v.z + v.w;
  }
  for (int off = 32; off > 0; off >>= 1) s += __shfl_down(s, off, 64);
  __shared__ float red[4];
  if ((tid & 63) == 0) red[tid >> 6] = s;
  __syncthreads();
  if (tid == 0) partial[bi] = red[0] + red[1] + red[2] + red[3];
}

__global__ void k_proj(const float* __restrict__ h_head, const float* __restrict__ h_dep,
                       const float* __restrict__ U, const float* __restrict__ V, const float* __restrict__ Z,
                       float* __restrict__ hU, float* __restrict__ hV, float* __restrict__ dZ) {
  const int which = blockIdx.y;
  const int r0 = blockIdx.x * 8;
  const int tid = threadIdx.x;
  const float* A = (which == 2) ? h_dep : h_head;
  const float* M = (which == 0) ? U : (which == 1) ? V : Z;
  float* out = (which == 0) ? hU : (which == 1) ? hV : dZ;
  __shared__ float ah[8][NI];
  #pragma unroll
  for (int r = 0; r < 8; ++r) ah[r][tid] = A[(r0 + r) * NI + tid];
  __syncthreads();
  float acc[8] = {};
  for (int i = 0; i < NI; ++i) {
    float m = M[i * NI + tid];
    #pragma unroll
    for (int r = 0; r < 8; ++r) acc[r] += ah[r][i] * m;
  }
  #pragma unroll
  for (int r = 0; r < 8; ++r) out[(r0 + r) * NI + tid] = acc[r];
}

__global__ void k_tobf16(const float* __restrict__ h_head, const float* __restrict__ h_dep,
                         const float* __restrict__ h_sib, const float* __restrict__ partial,
                         uint16_t* __restrict__ HW, uint16_t* __restrict__ HD, uint16_t* __restrict__ HS) {
  const int g = blockIdx.x * 256 + threadIdx.x;
  const int i = threadIdx.x;
  const float w = partial[4 * i] + partial[4 * i + 1] + partial[4 * i + 2] + partial[4 * i + 3];
  HW[g] = f2bf(h_head[g] * w);
  HD[g] = f2bf(h_dep[g]);
  HS[g] = f2bf(h_sib[g]);
}

__global__ void k_scores(const float* __restrict__ hU, const float* __restrict__ hV, const float* __restrict__ dZ,
                         const float* __restrict__ h_dep, const float* __restrict__ h_sib,
                         float* __restrict__ s_hd, float* __restrict__ s_hs, float* __restrict__ s_ds) {
  const int which = blockIdx.z, b = blockIdx.y, x0 = blockIdx.x * 8;
  const int tid = threadIdx.x;
  const float* A = (which == 0) ? hU : (which == 1) ? hV : dZ;
  const float* B = (which == 0) ? h_dep : h_sib;
  float* out = (which == 0) ? s_hd : (which == 1) ? s_hs : s_ds;
  __shared__ float ar[8][NI];
  for (int idx = tid; idx < 8 * NI; idx += 192)
    ar[idx >> 8][idx & 255] = A[(b * SS + x0 + (idx >> 8)) * NI + (idx & 255)];
  __syncthreads();
  const float4* bp = (const float4*)(B + (b * SS + tid) * NI);
  float acc[8] = {};
  for (int c = 0; c < NI / 4; ++c) {
    float4 bv = bp[c];
    #pragma unroll
    for (int r = 0; r < 8; ++r) {
      float4 av = ((const float4*)ar[r])[c];
      acc[r] += av.x * bv.x + av.y * bv.y + av.z * bv.z + av.w * bv.w;
    }
  }
  #pragma unroll
  for (int r = 0; r < 8; ++r) out[(b * SS + x0 + r) * SS + tid] = acc[r];
}

__global__ __launch_bounds__(256, 2) void k_big(
    const uint16_t* __restrict__ HW, const uint16_t* __restrict__ HD, const uint16_t* __restrict__ HS,
    const float* __restrict__ s_hd, const float* __restrict__ s_hs, const float* __restrict__ s_ds,
    const float* __restrict__ bias, float* __restrict__ out) {
  __shared__ __align__(16) unsigned char lds[32768];
  const int d = blockIdx.x, s0 = blockIdx.y * 64, b = blockIdx.z;
  const int tid = threadIdx.x;
  const int col8 = tid & 31;
  const uint4 hd4 = *(const uint4*)(HD + (b * SS + d) * NI + col8 * 8);
  #pragma unroll
  for (int it = 0; it < 8; ++it) {
    const int row = it * 8 + (tid >> 5);
    const uint4 hs4 = *(const uint4*)(HS + (b * SS + s0 + row) * NI + col8 * 8);
    uint4 a4;
    a4.x = bfmul2(hs4.x, hd4.x);
    a4.y = bfmul2(hs4.y, hd4.y);
    a4.z = bfmul2(hs4.z, hd4.z);
    a4.w = bfmul2(hs4.w, hd4.w);
    const int swz = ((row << 9) | (col8 << 4)) ^ ((row & 7) << 4);
    *(uint4*)(lds + swz) = a4;
  }
  __syncthreads();
  const int lane = tid & 63, w = tid >> 6;
  const int n0 = w * 48;
  const int fr = lane & 15;
  const int lg = lane >> 4;
  const int kb = lg * 8;
  const uint16_t* hwb = HW + (b * SS) * NI;
  f32x4 acc[4][3] = {};
  #pragma unroll
  for (int ks = 0; ks < 8; ++ks) {
    const int k = ks * 32 + kb;
    const int k2 = k * 2;
    bf16x8 a[4], bb[3];
    #pragma unroll
    for (int mt = 0; mt < 4; ++mt) {
      const int r = mt * 16 + fr;
      const int off = ((r << 9) + k2) ^ ((r & 7) << 4);
      a[mt] = *reinterpret_cast<const bf16x8*>(lds + off);
    }
    #pragma unroll
    for (int nt = 0; nt < 3; ++nt) {
      const int h = n0 + nt * 16 + fr;
      bb[nt] = *reinterpret_cast<const bf16x8*>(hwb + h * NI + k);
    }
    #pragma unroll
    for (int mt = 0; mt < 4; ++mt)
      #pragma unroll
      for (int nt = 0; nt < 3; ++nt)
        acc[mt][nt] = __builtin_amdgcn_mfma_f32_16x16x32_bf16(a[mt], bb[nt], acc[mt][nt], 0, 0, 0);
  }
  const float bias0 = bias[0];
  float c0[3];
  #pragma unroll
  for (int nt = 0; nt < 3; ++nt) {
    const int h = n0 + nt * 16 + fr;
    c0[nt] = s_hd[(b * SS + h) * SS + d] + bias0;
  }
  #pragma unroll
  for (int mt = 0; mt < 4; ++mt) {
    const int s = s0 + mt * 16 + lg * 4;
    const float4 ds4 = *(const float4*)(s_ds + (b * SS + d) * SS + s);
    #pragma unroll
    for (int nt = 0; nt < 3; ++nt) {
      const int h = n0 + nt * 16 + fr;
      const int bh = b * SS + h;
      const float4 hs4 = *(const float4*)(s_hs + bh * SS + s);
      float4 v;
      v.x = acc[mt][nt][0] + c0[nt] + hs4.x + ds4.x;
      v.y = acc[mt][nt][1] + c0[nt] + hs4.y + ds4.y;
      v.z = acc[mt][nt][2] + c0[nt] + hs4.z + ds4.z;
      v.w = acc[mt][nt][3] + c0[nt] + hs4.w + ds4.w;
      *(float4*)(out + ((size_t)bh * SS + d) * SS + s) = v;
    }
  }
}

extern "C" void kernel_launch(void* const* d_in, const int* in_sizes, int n_in,
                              void* d_out, int out_size, void* d_ws, size_t ws_size,
                              hipStream_t stream) {
  Params p;
  p.h_head = (const float*)d_in[0];
  p.h_dep  = (const float*)d_in[1];
  p.h_sib  = (const float*)d_in[2];
  p.W      = (const float*)d_in[3];
  p.U      = (const float*)d_in[4];
  p.V      = (const float*)d_in[5];
  p.Z      = (const float*)d_in[6];
  p.bias   = (const float*)d_in[7];
  p.out    = (float*)d_out;

  float* ws = (float*)d_ws;
  p.partial = ws;               ws += 2048;
  p.hU      = ws;               ws += 768 * NI;
  p.hV      = ws;               ws += 768 * NI;
  p.dZ      = ws;               ws += 768 * NI;
  p.s_hd    = ws;               ws += NB * SS * SS;
  p.s_hs    = ws;               ws += NB * SS * SS;
  p.s_ds    = ws;               ws += NB * SS * SS;
  p.HW      = (uint16_t*)ws;
  p.HD      = p.HW + 768 * NI;
  p.HS      = p.HD + 768 * NI;

  // --- try cooperative path (grid sized by the runtime's own occupancy calc) ---
  bool coop_ok = false;
  int dev = 0;
  (void)hipGetDevice(&dev);
  int coop_attr = 0;
  (void)hipDeviceGetAttribute(&coop_attr, hipDeviceAttributeCooperativeLaunch, dev);
  if (coop_attr) {
    int numCU = 0;
    (void)hipDeviceGetAttribute(&numCU, hipDeviceAttributeMultiprocessorCount, dev);
    int maxB = 0;
    if (hipOccupancyMaxActiveBlocksPerMultiprocessor(&maxB, (const void*)k_mega, 256, 0) == hipSuccess
        && maxB > 0 && numCU > 0) {
      int grid = numCU * maxB;
      if (grid > 2048) grid = 2048;
      void* args[] = { &p };
      coop_ok = (hipLaunchCooperativeKernel((const void*)k_mega, dim3(grid), dim3(256),
                                            args, 0, stream) == hipSuccess);
    }
  }

  if (!coop_ok) {
    // --- fallback: validated 5-kernel pipeline (R1) ---
    k_wtri_partial<<<1024, 256, 0, stream>>>(p.W, p.partial);
    k_proj<<<dim3(96, 3), 256, 0, stream>>>(p.h_head, p.h_dep, p.U, p.V, p.Z, p.hU, p.hV, p.dZ);
    k_tobf16<<<768, 256, 0, stream>>>(p.h_head, p.h_dep, p.h_sib, p.partial, p.HW, p.HD, p.HS);
    k_scores<<<dim3(24, 4, 3), 192, 0, stream>>>(p.hU, p.hV, p.dZ, p.h_dep, p.h_sib, p.s_hd, p.s_hs, p.s_ds);
    k_big<<<dim3(SS, 3, NB), 256, 0, stream>>>(p.HW, p.HD, p.HS, p.s_hd, p.s_hs, p.s_ds, p.bias, p.out);
  }
}

// Round 5
// 104.044 us; speedup vs baseline: 2.3564x; 2.3564x over previous
//
#include <hip/hip_runtime.h>
#include <stdint.h>

#define NB 4
#define SS 192
#define NI 256

typedef __attribute__((ext_vector_type(8))) short bf16x8;
typedef __attribute__((ext_vector_type(4))) float f32x4;

__device__ __forceinline__ uint16_t f2bf(float f) {
  union { float f; uint32_t u; } v; v.f = f;
  return (uint16_t)((v.u + 0x7FFFu + ((v.u >> 16) & 1u)) >> 16);
}

__device__ __forceinline__ uint32_t bfmul2(uint32_t x, uint32_t y) {
  union { float f; uint32_t u; } xa, xb, ya, yb, r0, r1;
  xa.u = x << 16;        ya.u = y << 16;
  xb.u = x & 0xFFFF0000u; yb.u = y & 0xFFFF0000u;
  r0.f = xa.f * ya.f;
  r1.f = xb.f * yb.f;
  uint32_t lo = (r0.u + 0x7FFFu + ((r0.u >> 16) & 1u)) >> 16;
  uint32_t hi = (r1.u + 0x7FFFu + ((r1.u >> 16) & 1u)) >> 16;
  return lo | (hi << 16);
}

// ---------------- K1: W_tri partial sums + HD/HS bf16 convert ----------------
// 1024 blocks. Each sums one 16384-float chunk of W_tri; blocks 0..767 also
// convert one row of h_dep/h_sib to bf16.
__global__ void k1_wtri_conv(const float* __restrict__ W, const float* __restrict__ h_dep,
                             const float* __restrict__ h_sib,
                             float* __restrict__ partial,
                             uint16_t* __restrict__ HD, uint16_t* __restrict__ HS) {
  const int bi = blockIdx.x, tid = threadIdx.x;
  const float4* p = (const float4*)(W + (size_t)bi * 16384);
  float s = 0.f;
  #pragma unroll
  for (int it = 0; it < 16; ++it) {
    float4 v = p[it * 256 + tid];
    s += v.x + v.y + v.z + v.w;
  }
  for (int off = 32; off > 0; off >>= 1) s += __shfl_down(s, off, 64);
  __shared__ float red[4];
  if ((tid & 63) == 0) red[tid >> 6] = s;
  __syncthreads();
  if (tid == 0) partial[bi] = red[0] + red[1] + red[2] + red[3];
  if (bi < NB * SS) {
    const int g = bi * NI + tid;
    HD[g] = f2bf(h_dep[g]);
    HS[g] = f2bf(h_sib[g]);
  }
}

// ---------------- K2: w_red finish + HW convert + fused proj->scores ----------------
// 576 blocks x 256 threads. Block u: one (which, b, x0) projection+score unit.
__global__ void k2_scores(const float* __restrict__ h_head, const float* __restrict__ h_dep,
                          const float* __restrict__ h_sib,
                          const float* __restrict__ U, const float* __restrict__ V, const float* __restrict__ Z,
                          const float* __restrict__ partial,
                          uint16_t* __restrict__ HW,
                          float* __restrict__ s_hd, float* __restrict__ s_hs, float* __restrict__ s_ds) {
  const int bi = blockIdx.x, tid = threadIdx.x;
  __shared__ float wred[NI];
  __shared__ float ahf[4 * NI];
  __shared__ float tf[4 * NI];
  wred[tid] = partial[4 * tid] + partial[4 * tid + 1] + partial[4 * tid + 2] + partial[4 * tid + 3];
  __syncthreads();
  for (int r = bi; r < NB * SS; r += 576) {
    const int g = r * NI + tid;
    HW[g] = f2bf(h_head[g] * wred[tid]);
  }
  // fused projection -> score for unit bi
  const int which = bi / 192, rem = bi % 192;
  const int b = rem / 48, x0 = (rem % 48) * 4;
  const float* A  = (which == 2) ? h_dep : h_head;
  const float* M  = (which == 0) ? U : (which == 1) ? V : Z;
  const float* Bm = (which == 0) ? h_dep : h_sib;
  float* outp = (which == 0) ? s_hd : (which == 1) ? s_hs : s_ds;
  #pragma unroll
  for (int r = 0; r < 4; ++r) ahf[r * NI + tid] = A[(b * SS + x0 + r) * NI + tid];
  __syncthreads();
  float ta[4] = {};
  for (int i = 0; i < NI; ++i) {
    const float m = M[i * NI + tid];
    #pragma unroll
    for (int r = 0; r < 4; ++r) ta[r] += ahf[r * NI + i] * m;
  }
  #pragma unroll
  for (int r = 0; r < 4; ++r) tf[r * NI + tid] = ta[r];
  __syncthreads();
  if (tid < SS) {
    const float4* brow = (const float4*)(Bm + (b * SS + tid) * NI);
    float acc[4] = {};
    for (int c = 0; c < NI / 4; ++c) {
      const float4 bv = brow[c];
      #pragma unroll
      for (int r = 0; r < 4; ++r) {
        const float4 av = ((const float4*)(tf + r * NI))[c];
        acc[r] += av.x * bv.x + av.y * bv.y + av.z * bv.z + av.w * bv.w;
      }
    }
    #pragma unroll
    for (int r = 0; r < 4; ++r) outp[(b * SS + x0 + r) * SS + tid] = acc[r];
  }
}

// ---------------- K3: main GEMM (validated R1 structure, higher occupancy) ----------------
// grid (192, 3, 4) = (d, s-tile, b). 256 threads = 4 waves, each M=64 x N=48.
__global__ __launch_bounds__(256, 4) void k_big(
    const uint16_t* __restrict__ HW, const uint16_t* __restrict__ HD, const uint16_t* __restrict__ HS,
    const float* __restrict__ s_hd, const float* __restrict__ s_hs, const float* __restrict__ s_ds,
    const float* __restrict__ bias, float* __restrict__ out) {
  __shared__ __align__(16) unsigned char lds[32768];
  const int d = blockIdx.x, s0 = blockIdx.y * 64, b = blockIdx.z;
  const int tid = threadIdx.x;

  const int col8 = tid & 31;
  const uint4 hd4 = *(const uint4*)(HD + (b * SS + d) * NI + col8 * 8);
  #pragma unroll
  for (int it = 0; it < 8; ++it) {
    const int row = it * 8 + (tid >> 5);
    const uint4 hs4 = *(const uint4*)(HS + (b * SS + s0 + row) * NI + col8 * 8);
    uint4 a4;
    a4.x = bfmul2(hs4.x, hd4.x);
    a4.y = bfmul2(hs4.y, hd4.y);
    a4.z = bfmul2(hs4.z, hd4.z);
    a4.w = bfmul2(hs4.w, hd4.w);
    const int swz = ((row << 9) | (col8 << 4)) ^ ((row & 7) << 4);
    *(uint4*)(lds + swz) = a4;
  }
  __syncthreads();

  const int lane = tid & 63, w = tid >> 6;
  const int n0 = w * 48;
  const int fr = lane & 15;
  const int lg = lane >> 4;
  const int kb = lg * 8;
  const uint16_t* hwb = HW + (b * SS) * NI;
  f32x4 acc[4][3] = {};
  #pragma unroll
  for (int ks = 0; ks < 8; ++ks) {
    const int k = ks * 32 + kb;
    const int k2 = k * 2;
    bf16x8 a[4], bb[3];
    #pragma unroll
    for (int mt = 0; mt < 4; ++mt) {
      const int r = mt * 16 + fr;
      const int off = ((r << 9) + k2) ^ ((r & 7) << 4);
      a[mt] = *reinterpret_cast<const bf16x8*>(lds + off);
    }
    #pragma unroll
    for (int nt = 0; nt < 3; ++nt) {
      const int h = n0 + nt * 16 + fr;
      bb[nt] = *reinterpret_cast<const bf16x8*>(hwb + h * NI + k);
    }
    #pragma unroll
    for (int mt = 0; mt < 4; ++mt)
      #pragma unroll
      for (int nt = 0; nt < 3; ++nt)
        acc[mt][nt] = __builtin_amdgcn_mfma_f32_16x16x32_bf16(a[mt], bb[nt], acc[mt][nt], 0, 0, 0);
  }

  const float bias0 = bias[0];
  float c0[3];
  #pragma unroll
  for (int nt = 0; nt < 3; ++nt) {
    const int h = n0 + nt * 16 + fr;
    c0[nt] = s_hd[(b * SS + h) * SS + d] + bias0;
  }
  #pragma unroll
  for (int mt = 0; mt < 4; ++mt) {
    const int s = s0 + mt * 16 + lg * 4;
    const float4 ds4 = *(const float4*)(s_ds + (b * SS + d) * SS + s);
    #pragma unroll
    for (int nt = 0; nt < 3; ++nt) {
      const int h = n0 + nt * 16 + fr;
      const int bh = b * SS + h;
      const float4 hs4 = *(const float4*)(s_hs + bh * SS + s);
      float4 v;
      v.x = acc[mt][nt][0] + c0[nt] + hs4.x + ds4.x;
      v.y = acc[mt][nt][1] + c0[nt] + hs4.y + ds4.y;
      v.z = acc[mt][nt][2] + c0[nt] + hs4.z + ds4.z;
      v.w = acc[mt][nt][3] + c0[nt] + hs4.w + ds4.w;
      *(float4*)(out + ((size_t)bh * SS + d) * SS + s) = v;
    }
  }
}

extern "C" void kernel_launch(void* const* d_in, const int* in_sizes, int n_in,
                              void* d_out, int out_size, void* d_ws, size_t ws_size,
                              hipStream_t stream) {
  const float* h_head = (const float*)d_in[0];
  const float* h_dep  = (const float*)d_in[1];
  const float* h_sib  = (const float*)d_in[2];
  const float* W_tri  = (const float*)d_in[3];
  const float* U_hd   = (const float*)d_in[4];
  const float* V_hs   = (const float*)d_in[5];
  const float* Z_ds   = (const float*)d_in[6];
  const float* bias   = (const float*)d_in[7];
  float* out = (float*)d_out;

  float* ws = (float*)d_ws;
  float* partial = ws;          ws += 1024;
  float* s_hd    = ws;          ws += NB * SS * SS;
  float* s_hs    = ws;          ws += NB * SS * SS;
  float* s_ds    = ws;          ws += NB * SS * SS;
  uint16_t* HW   = (uint16_t*)ws;
  uint16_t* HD   = HW + 768 * NI;
  uint16_t* HS   = HD + 768 * NI;

  k1_wtri_conv<<<1024, 256, 0, stream>>>(W_tri, h_dep, h_sib, partial, HD, HS);
  k2_scores<<<576, 256, 0, stream>>>(h_head, h_dep, h_sib, U_hd, V_hs, Z_ds, partial,
                                     HW, s_hd, s_hs, s_ds);
  k_big<<<dim3(SS, 3, NB), 256, 0, stream>>>(HW, HD, HS, s_hd, s_hs, s_ds, bias, out);
}

// Round 6
// 95.152 us; speedup vs baseline: 2.5766x; 1.0934x over previous
//
#include <hip/hip_runtime.h>
#include <stdint.h>

#define NB 4
#define SS 192
#define NI 256

typedef __attribute__((ext_vector_type(8))) short bf16x8;
typedef __attribute__((ext_vector_type(16))) float f32x16;

__device__ __forceinline__ uint16_t f2bf(float f) {
  union { float f; uint32_t u; } v; v.f = f;
  return (uint16_t)((v.u + 0x7FFFu + ((v.u >> 16) & 1u)) >> 16);
}

__device__ __forceinline__ uint32_t bfmul2(uint32_t x, uint32_t y) {
  union { float f; uint32_t u; } xa, xb, ya, yb, r0, r1;
  xa.u = x << 16;        ya.u = y << 16;
  xb.u = x & 0xFFFF0000u; yb.u = y & 0xFFFF0000u;
  r0.f = xa.f * ya.f;
  r1.f = xb.f * yb.f;
  uint32_t lo = (r0.u + 0x7FFFu + ((r0.u >> 16) & 1u)) >> 16;
  uint32_t hi = (r1.u + 0x7FFFu + ((r1.u >> 16) & 1u)) >> 16;
  return lo | (hi << 16);
}

// ---------------- K1: W_tri partial sums + HD/HS bf16 convert (validated) ----------------
__global__ void k1_wtri_conv(const float* __restrict__ W, const float* __restrict__ h_dep,
                             const float* __restrict__ h_sib,
                             float* __restrict__ partial,
                             uint16_t* __restrict__ HD, uint16_t* __restrict__ HS) {
  const int bi = blockIdx.x, tid = threadIdx.x;
  const float4* p = (const float4*)(W + (size_t)bi * 16384);
  float s = 0.f;
  #pragma unroll
  for (int it = 0; it < 16; ++it) {
    float4 v = p[it * 256 + tid];
    s += v.x + v.y + v.z + v.w;
  }
  for (int off = 32; off > 0; off >>= 1) s += __shfl_down(s, off, 64);
  __shared__ float red[4];
  if ((tid & 63) == 0) red[tid >> 6] = s;
  __syncthreads();
  if (tid == 0) partial[bi] = red[0] + red[1] + red[2] + red[3];
  if (bi < NB * SS) {
    const int g = bi * NI + tid;
    HD[g] = f2bf(h_dep[g]);
    HS[g] = f2bf(h_sib[g]);
  }
}

// ---------------- K2: w_red finish + HW convert + fused proj->scores (validated) ----------------
__global__ void k2_scores(const float* __restrict__ h_head, const float* __restrict__ h_dep,
                          const float* __restrict__ h_sib,
                          const float* __restrict__ U, const float* __restrict__ V, const float* __restrict__ Z,
                          const float* __restrict__ partial,
                          uint16_t* __restrict__ HW,
                          float* __restrict__ s_hd, float* __restrict__ s_hs, float* __restrict__ s_ds) {
  const int bi = blockIdx.x, tid = threadIdx.x;
  __shared__ float wred[NI];
  __shared__ float ahf[4 * NI];
  __shared__ float tf[4 * NI];
  wred[tid] = partial[4 * tid] + partial[4 * tid + 1] + partial[4 * tid + 2] + partial[4 * tid + 3];
  __syncthreads();
  for (int r = bi; r < NB * SS; r += 576) {
    const int g = r * NI + tid;
    HW[g] = f2bf(h_head[g] * wred[tid]);
  }
  const int which = bi / 192, rem = bi % 192;
  const int b = rem / 48, x0 = (rem % 48) * 4;
  const float* A  = (which == 2) ? h_dep : h_head;
  const float* M  = (which == 0) ? U : (which == 1) ? V : Z;
  const float* Bm = (which == 0) ? h_dep : h_sib;
  float* outp = (which == 0) ? s_hd : (which == 1) ? s_hs : s_ds;
  #pragma unroll
  for (int r = 0; r < 4; ++r) ahf[r * NI + tid] = A[(b * SS + x0 + r) * NI + tid];
  __syncthreads();
  float ta[4] = {};
  for (int i = 0; i < NI; ++i) {
    const float m = M[i * NI + tid];
    #pragma unroll
    for (int r = 0; r < 4; ++r) ta[r] += ahf[r * NI + i] * m;
  }
  #pragma unroll
  for (int r = 0; r < 4; ++r) tf[r * NI + tid] = ta[r];
  __syncthreads();
  if (tid < SS) {
    const float4* brow = (const float4*)(Bm + (b * SS + tid) * NI);
    float acc[4] = {};
    for (int c = 0; c < NI / 4; ++c) {
      const float4 bv = brow[c];
      #pragma unroll
      for (int r = 0; r < 4; ++r) {
        const float4 av = ((const float4*)(tf + r * NI))[c];
        acc[r] += av.x * bv.x + av.y * bv.y + av.z * bv.z + av.w * bv.w;
      }
    }
    #pragma unroll
    for (int r = 0; r < 4; ++r) outp[(b * SS + x0 + r) * SS + tid] = acc[r];
  }
}

// ---------------- K3: 32x32x16 MFMA, 128B stores, global_load_lds B-tile ----------------
// grid (192, 2, 4) = (d, h-half, b). 384 threads = 6 waves (3 h-strips x 2 s-strips).
// out[b,h,d,s] = sum_k (HW[bh,k]*HD[bd,k]) * HS[bs,k] + s_hd + s_hs + s_ds + bias
__global__ __launch_bounds__(384, 3) void k3_big(
    const uint16_t* __restrict__ HW, const uint16_t* __restrict__ HD, const uint16_t* __restrict__ HS,
    const float* __restrict__ s_hd, const float* __restrict__ s_hs, const float* __restrict__ s_ds,
    const float* __restrict__ bias, float* __restrict__ out) {
  __shared__ __align__(16) uint16_t Btile[SS * 128];   // 192 rows x 256B = 48 KB (HS, swizzled)
  __shared__ __align__(16) uint16_t Atile[96 * 128];   // 96 rows x 256B = 24 KB (HW*HD, swizzled)
  const int d = blockIdx.x, hh = blockIdx.y, b = blockIdx.z;
  const int tid = threadIdx.x;
  const int lane = tid & 63, w = tid >> 6;
  const int whb = (w >> 1) * 32;          // h-strip base within half (0/32/64)
  const int wsb = (w & 1) * 96;           // s-strip base (0/96)
  const int l31 = lane & 31, l5 = lane >> 5;
  const int kc = tid & 15;                // fixed 16B-slot index per thread
  const uint16_t* hd_row = HD + ((b * SS + d) << 8);

  f32x16 acc0 = {}, acc1 = {}, acc2 = {};

  #pragma unroll
  for (int half = 0; half < 2; ++half) {
    const int kbase = half * 128;
    // ---- B-tile: pure HS copy via global_load_lds (dest linear, source pre-swizzled) ----
    #pragma unroll
    for (int i = 0; i < 8; ++i) {
      const int slot = (w * 8 + i) * 64 + lane;
      const int row = slot >> 4;
      const int kcs = (slot & 15) ^ (row & 15);
      const uint16_t* src = HS + ((b * SS + row) << 8) + kbase + kcs * 8;
      __builtin_amdgcn_global_load_lds(
          (const __attribute__((address_space(1))) void*)src,
          (__attribute__((address_space(3))) void*)(Btile + (size_t)(w * 8 + i) * 512),
          16, 0, 0);
    }
    // ---- A-tile: HW ⊙ HD_d, swizzled ds_write ----
    const uint4 hd4 = *(const uint4*)(hd_row + kbase + kc * 8);
    #pragma unroll
    for (int i = 0; i < 4; ++i) {
      const int c = i * 384 + tid;
      const int row = c >> 4;               // 0..95
      const uint4 hw4 = *(const uint4*)(HW + ((b * SS + hh * 96 + row) << 8) + kbase + kc * 8);
      uint4 a4;
      a4.x = bfmul2(hw4.x, hd4.x);
      a4.y = bfmul2(hw4.y, hd4.y);
      a4.z = bfmul2(hw4.z, hd4.z);
      a4.w = bfmul2(hw4.w, hd4.w);
      *(uint4*)((char*)Atile + row * 256 + ((kc ^ (row & 15)) << 4)) = a4;
    }
    __syncthreads();
    // ---- MFMA: 8 k-steps x 3 s-tiles of 32x32x16 ----
    const int arow = whb + l31;
    const int abyte = arow * 256;
    const int amask = (arow & 15);
    #pragma unroll
    for (int ks = 0; ks < 8; ++ks) {
      const int sl = ks * 2 + l5;
      bf16x8 af = *reinterpret_cast<const bf16x8*>((const char*)Atile + abyte + ((sl ^ amask) << 4));
      {
        const int brow = wsb + l31;
        bf16x8 bf = *reinterpret_cast<const bf16x8*>((const char*)Btile + brow * 256 + ((sl ^ (brow & 15)) << 4));
        acc0 = __builtin_amdgcn_mfma_f32_32x32x16_bf16(af, bf, acc0, 0, 0, 0);
      }
      {
        const int brow = wsb + 32 + l31;
        bf16x8 bf = *reinterpret_cast<const bf16x8*>((const char*)Btile + brow * 256 + ((sl ^ (brow & 15)) << 4));
        acc1 = __builtin_amdgcn_mfma_f32_32x32x16_bf16(af, bf, acc1, 0, 0, 0);
      }
      {
        const int brow = wsb + 64 + l31;
        bf16x8 bf = *reinterpret_cast<const bf16x8*>((const char*)Btile + brow * 256 + ((sl ^ (brow & 15)) << 4));
        acc2 = __builtin_amdgcn_mfma_f32_32x32x16_bf16(af, bf, acc2, 0, 0, 0);
      }
    }
    __syncthreads();
  }

  // ---- epilogue: + s_hd[b,h,d] + bias (per h) + s_hs[b,h,s] + s_ds[b,d,s] ----
  const float bias0 = bias[0];
  float chd[16];
  #pragma unroll
  for (int r = 0; r < 16; ++r) {
    const int h = hh * 96 + whb + (r & 3) + 8 * (r >> 2) + 4 * l5;
    chd[r] = s_hd[(b * SS + h) * SS + d] + bias0;
  }
  #pragma unroll
  for (int t = 0; t < 3; ++t) {
    const int s = wsb + t * 32 + l31;
    const float dsv = s_ds[(b * SS + d) * SS + s];
    const f32x16 a = (t == 0) ? acc0 : (t == 1) ? acc1 : acc2;
    #pragma unroll
    for (int r = 0; r < 16; ++r) {
      const int h = hh * 96 + whb + (r & 3) + 8 * (r >> 2) + 4 * l5;
      const float v = a[r] + chd[r] + s_hs[(b * SS + h) * SS + s] + dsv;
      out[((size_t)(b * SS + h) * SS + d) * SS + s] = v;
    }
  }
}

extern "C" void kernel_launch(void* const* d_in, const int* in_sizes, int n_in,
                              void* d_out, int out_size, void* d_ws, size_t ws_size,
                              hipStream_t stream) {
  const float* h_head = (const float*)d_in[0];
  const float* h_dep  = (const float*)d_in[1];
  const float* h_sib  = (const float*)d_in[2];
  const float* W_tri  = (const float*)d_in[3];
  const float* U_hd   = (const float*)d_in[4];
  const float* V_hs   = (const float*)d_in[5];
  const float* Z_ds   = (const float*)d_in[6];
  const float* bias   = (const float*)d_in[7];
  float* out = (float*)d_out;

  float* ws = (float*)d_ws;
  float* partial = ws;          ws += 1024;
  float* s_hd    = ws;          ws += NB * SS * SS;
  float* s_hs    = ws;          ws += NB * SS * SS;
  float* s_ds    = ws;          ws += NB * SS * SS;
  uint16_t* HW   = (uint16_t*)ws;
  uint16_t* HD   = HW + 768 * NI;
  uint16_t* HS   = HD + 768 * NI;

  k1_wtri_conv<<<1024, 256, 0, stream>>>(W_tri, h_dep, h_sib, partial, HD, HS);
  k2_scores<<<576, 256, 0, stream>>>(h_head, h_dep, h_sib, U_hd, V_hs, Z_ds, partial,
                                     HW, s_hd, s_hs, s_ds);
  k3_big<<<dim3(SS, 2, NB), 384, 0, stream>>>(HW, HD, HS, s_hd, s_hs, s_ds, bias, out);
}